// Round 14
// baseline (108.348 us; speedup 1.0000x reference)
//
#include <hip/hip_runtime.h>

typedef __attribute__((ext_vector_type(8))) __bf16 bf16x8;
typedef __attribute__((ext_vector_type(4))) __bf16 bf16x4;
typedef __attribute__((ext_vector_type(4))) float f32x4;

#define MFMA16x16x32(A, B, C) __builtin_amdgcn_mfma_f32_16x16x32_bf16(A, B, C, 0, 0, 0)

__device__ __forceinline__ unsigned short f2bf(float f) {
    unsigned int u = __float_as_uint(f);
    u += 0x7fffu + ((u >> 16) & 1u);
    return (unsigned short)(u >> 16);
}

__device__ __forceinline__ unsigned cvtpk_bf16(float lo, float hi) {
    unsigned r;
    asm("v_cvt_pk_bf16_f32 %0, %1, %2" : "=v"(r) : "v"(lo), "v"(hi));
    return r;
}

// raw hardware exp2 (v_exp_f32, ~1 ulp) — avoids OCML guarded sequence (~10 instr)
__device__ __forceinline__ float exp2_hw(float x) {
    float r;
    asm("v_exp_f32 %0, %1" : "=v"(r) : "v"(x));
    return r;
}

__device__ __forceinline__ void gload16(const void* src, void* lds) {
    __builtin_amdgcn_global_load_lds(
        (const __attribute__((address_space(1))) unsigned int*)src,
        (__attribute__((address_space(3))) unsigned int*)lds,
        16, 0, 0);
}

// ---------------- stage 1+2 merged: x cvt + all W transposes, one launch -------
__global__ __launch_bounds__(256) void prep_kernel(
    const float* __restrict__ x, unsigned short* __restrict__ xb,
    const float* __restrict__ Wq, const float* __restrict__ Wk,
    const float* __restrict__ Wv, const float* __restrict__ Wo,
    unsigned short* __restrict__ Wqt, unsigned short* __restrict__ Wkt,
    unsigned short* __restrict__ Wvt, unsigned short* __restrict__ Wot)
{
    __shared__ float tile[32][33];
    const int blk = blockIdx.x;
    const int tid = threadIdx.x;

    if (blk < 4096) {
        const int i = (blk * 256 + tid) * 4;
        const float4 v = *(const float4*)(x + i);
        ushort4 o;
        o.x = f2bf(v.x); o.y = f2bf(v.y); o.z = f2bf(v.z); o.w = f2bf(v.w);
        *(ushort4*)(xb + i) = o;
        return;
    }

    const int blk2 = blk - 4096;
    const int kx = blk2 & 31;         // 0..31 k-tile
    int y = blk2 >> 5;                // 0..111
    const float* W; unsigned short* Wt; int N;
    if (y < 32)      { W = Wq; Wt = Wqt; N = 1024; }
    else if (y < 64) { W = Wk; Wt = Wkt; N = 1024; y -= 32; }
    else if (y < 96) { W = Wv; Wt = Wvt; N = 1024; y -= 64; }
    else             { W = Wo; Wt = Wot; N = 512;  y -= 96; }
    const int k0 = kx * 32;
    const int n0 = y * 32;
    const int tx = tid & 31, ty = tid >> 5;
#pragma unroll
    for (int i = 0; i < 4; ++i)
        tile[ty + 8 * i][tx] = W[(size_t)(k0 + ty + 8 * i) * N + n0 + tx];
    __syncthreads();
#pragma unroll
    for (int i = 0; i < 4; ++i)
        Wt[(size_t)(n0 + ty + 8 * i) * 1024 + k0 + tx] = f2bf(tile[tx][ty + 8 * i]);
}

// ---------------- stage 3: fused QKV GEMM ----------------
// X [4096][1024] bf16  x  Wt [1024 n][1024 k] bf16  -> Q/K [b][h][s][d] bf16 (+bias)
// V is written TRANSPOSED directly to Vt [b][h][d][s]. Q pre-scaled by log2(e)/8.
__global__ __launch_bounds__(256, 3) void gemm_qkv_kernel(
    const unsigned short* __restrict__ xb,
    const unsigned short* __restrict__ Wqt,
    const unsigned short* __restrict__ Wkt,
    const unsigned short* __restrict__ Wvt,
    const float* __restrict__ bq, const float* __restrict__ bk, const float* __restrict__ bv,
    unsigned short* __restrict__ Qb, unsigned short* __restrict__ Kb, unsigned short* __restrict__ Vt)
{
    __shared__ unsigned short sA[2][128 * 32];
    __shared__ unsigned short sB[2][128 * 32];

    const int tid  = threadIdx.x;
    const int lane = tid & 63;
    const int w    = tid >> 6;
    const int wm   = w >> 1, wn = w & 1;
    const int li   = lane & 15, gg = lane >> 4;

    // XCD swizzle: 768 blocks -> XCD c owns v in [c*96, (c+1)*96), vy-fast.
    const int L  = blockIdx.y * 24 + blockIdx.x;
    const int v  = (L & 7) * 96 + (L >> 3);
    const int vx = v >> 5;            // 0..23  (which*8 + n-panel)
    const int vy = v & 31;            // 0..31  (m-tile)
    const int m0    = vy * 128;
    const int which = vx >> 3;
    const int nloc0 = (vx & 7) * 128;

    const unsigned short* Wt = (which == 0) ? Wqt : ((which == 1) ? Wkt : Wvt);
    const float* bias        = (which == 0) ? bq  : ((which == 1) ? bk  : bv);
    const float osc          = (which == 0) ? 0.18033688011112042f : 1.0f; // log2(e)/8

    const int srow = lane >> 2;   // row within 16-row chunk
    const int schk = lane & 3;    // 16B chunk within 64B row

    f32x4 acc[4][4];
#pragma unroll
    for (int i = 0; i < 4; ++i)
#pragma unroll
        for (int j = 0; j < 4; ++j)
            acc[i][j] = (f32x4){0.f, 0.f, 0.f, 0.f};

    int aoff[4], boff[4];
#pragma unroll
    for (int f = 0; f < 4; ++f) {
        const int ra = wm * 64 + f * 16 + li;
        aoff[f] = ra * 32 + ((gg ^ ((ra >> 1) & 3)) * 8);
        const int rb = wn * 64 + f * 16 + li;
        boff[f] = rb * 32 + ((gg ^ ((rb >> 1) & 3)) * 8);
    }

#pragma unroll
    for (int j = 0; j < 2; ++j) {
        const int rl = (w * 2 + j) * 16 + srow;
        const int c  = schk ^ ((rl >> 1) & 3);
        gload16(xb + (size_t)(m0 + rl) * 1024 + c * 8,   sA[0] + (w * 2 + j) * 512);
        gload16(Wt + (size_t)(nloc0 + rl) * 1024 + c * 8, sB[0] + (w * 2 + j) * 512);
    }
    __syncthreads();

    for (int kt = 0; kt < 32; ++kt) {
        const int cur = kt & 1;
        if (kt < 31) {
            const int k1 = (kt + 1) * 32;
#pragma unroll
            for (int j = 0; j < 2; ++j) {
                const int rl = (w * 2 + j) * 16 + srow;
                const int c  = schk ^ ((rl >> 1) & 3);
                gload16(xb + (size_t)(m0 + rl) * 1024 + k1 + c * 8,   sA[cur ^ 1] + (w * 2 + j) * 512);
                gload16(Wt + (size_t)(nloc0 + rl) * 1024 + k1 + c * 8, sB[cur ^ 1] + (w * 2 + j) * 512);
            }
        }
        bf16x8 av[4], bw[4];
#pragma unroll
        for (int f = 0; f < 4; ++f) av[f] = *(const bf16x8*)(sA[cur] + aoff[f]);
#pragma unroll
        for (int f = 0; f < 4; ++f) bw[f] = *(const bf16x8*)(sB[cur] + boff[f]);
#pragma unroll
        for (int mf = 0; mf < 4; ++mf)
#pragma unroll
            for (int nf = 0; nf < 4; ++nf)
                acc[mf][nf] = MFMA16x16x32(av[mf], bw[nf], acc[mf][nf]);
        __syncthreads();
    }

    // epilogue: C frag col = lane&15, row = (lane>>4)*4 + r
    if (which == 2) {
        // V: write transposed straight to Vt[b*16+h][d][s]; r gives 4 consecutive s.
#pragma unroll
        for (int nf = 0; nf < 4; ++nf) {
            const int nl = nloc0 + wn * 64 + nf * 16 + li;
            const float bi = bias[nl];
            const int h = nl >> 6, d = nl & 63;
#pragma unroll
            for (int mf = 0; mf < 4; ++mf) {
                const int m = m0 + wm * 64 + mf * 16 + gg * 4;
                const int b = m >> 11, s0 = m & 2047;
                ushort4 o;
                o.x = f2bf(acc[mf][nf][0] + bi);
                o.y = f2bf(acc[mf][nf][1] + bi);
                o.z = f2bf(acc[mf][nf][2] + bi);
                o.w = f2bf(acc[mf][nf][3] + bi);
                *(ushort4*)(Vt + (((size_t)(b * 16 + h)) * 64 + d) * 2048 + s0) = o;
            }
        }
    } else {
        unsigned short* dst = (which == 0) ? Qb : Kb;
#pragma unroll
        for (int nf = 0; nf < 4; ++nf) {
            const int nl = nloc0 + wn * 64 + nf * 16 + li;
            const float bi = bias[nl];
            const int h = nl >> 6, d = nl & 63;
#pragma unroll
            for (int mf = 0; mf < 4; ++mf) {
#pragma unroll
                for (int r = 0; r < 4; ++r) {
                    const int m = m0 + wm * 64 + mf * 16 + gg * 4 + r;
                    const int b = m >> 11, s = m & 2047;
                    dst[(((size_t)(b * 16 + h)) * 2048 + s) * 64 + d] = f2bf((acc[mf][nf][r] + bi) * osc);
                }
            }
        }
    }
}

// ---------------- stage 5: flash attention v12 — 8 waves x 32 q --------------
// 512 threads = 8 waves, each owning 32 q (2 mq sub-tiles); block covers 256 q.
// Grid 256 (1 block/CU, 8 waves/CU). Halves per-wave LDS K/V reads per q vs the
// 16-q config (attn was 87% LDS-read-saturated). launch_bounds(512,2) -> VGPR
// cap 256, no spill (r10's failure). Staging = r13-verified KVBLK=128 double
// half-tiles; inner body = r10-verified 2-mq shift-free softmax + in-reg P.
__global__ __launch_bounds__(512, 2) void attn_kernel(
    const unsigned short* __restrict__ Qb,
    const unsigned short* __restrict__ Kb,
    const unsigned short* __restrict__ Vt,
    unsigned short* __restrict__ Ob)
{
    __shared__ unsigned short sK[2][2][64 * 64];   // [buf][half][64 keys x 64 d]
    __shared__ unsigned short sV[2][2][64 * 64];   // [buf][half][64 d x 64 s]

    const int tid  = threadIdx.x;
    const int lane = tid & 63;
    const int w    = tid >> 6;        // 0..7
    const int li   = lane & 15, gg = lane >> 4;

    // XCD swizzle: 256 blocks -> XCD c owns v in [c*32,(c+1)*32) = 4 bh.
    const int L  = blockIdx.x;
    const int v  = (L & 7) * 32 + (L >> 3);
    const int bh = v >> 3;
    const int q0 = (v & 7) * 256 + w * 32;

    // staging: 512 threads, one 16B chunk per (array, half): 4 gload16 per tile.
    const int slot = tid;             // 0..511
    const int srow = slot >> 3;       // 0..63
    const int schk = (slot & 7) ^ (srow & 7);

    const unsigned short* Kbase = Kb + ((size_t)bh * 2048 + srow) * 64 + schk * 8;
    const unsigned short* Vbase = Vt + ((size_t)bh * 64 + srow) * 2048 + schk * 8;

    // Q fragments (pre-scaled by log2(e)/8): 2 mq x 2 kk
    bf16x8 qf[2][2];
#pragma unroll
    for (int mq = 0; mq < 2; ++mq)
#pragma unroll
        for (int kk = 0; kk < 2; ++kk) {
            const int q = q0 + mq * 16 + li;
            const int d = kk * 32 + gg * 8;
            qf[mq][kk] = *(const bf16x8*)(Qb + ((size_t)bh * 2048 + q) * 64 + d);
        }

    f32x4 acc[2][4];
    float l_s[2];
#pragma unroll
    for (int mq = 0; mq < 2; ++mq) {
#pragma unroll
        for (int df = 0; df < 4; ++df) acc[mq][df] = (f32x4){0.f, 0.f, 0.f, 0.f};
        l_s[mq] = 0.f;
    }

    // prologue: stage tile 0 (both 64-key halves)
    gload16(Kbase,          sK[0][0] + slot * 8);
    gload16(Kbase + 4096,   sK[0][1] + slot * 8);
    gload16(Vbase,          sV[0][0] + slot * 8);
    gload16(Vbase + 64,     sV[0][1] + slot * 8);
    __syncthreads();

    for (int tt = 0; tt < 16; ++tt) {
        const int cur = tt & 1;
        if (tt < 15) {
            const size_t ko = (size_t)(tt + 1) * 8192;   // 128 keys * 64 d
            const size_t vo = (size_t)(tt + 1) * 128;    // 128 s
            gload16(Kbase + ko,        sK[cur ^ 1][0] + slot * 8);
            gload16(Kbase + ko + 4096, sK[cur ^ 1][1] + slot * 8);
            gload16(Vbase + vo,        sV[cur ^ 1][0] + slot * 8);
            gload16(Vbase + vo + 64,   sV[cur ^ 1][1] + slot * 8);
        }

#pragma unroll
        for (int sub = 0; sub < 2; ++sub) {
            const unsigned short* sKh = sK[cur][sub];
            const unsigned short* sVh = sV[cur][sub];

            // ---- kf: full 64-key K half-tile (shared across both mq) ----
            bf16x8 kf[4][2];
#pragma unroll
            for (int nf = 0; nf < 4; ++nf)
#pragma unroll
                for (int kk = 0; kk < 2; ++kk) {
                    const int n = nf * 16 + li;
                    const int ch = kk * 4 + gg;
                    kf[nf][kk] = *(const bf16x8*)(sKh + n * 64 + ((ch ^ (n & 7)) * 8));
                }

            // ---- per mq: S^T = mfma(K,Q), exp2, pack, in-register P ----
            bf16x8 pf[2][2];
#pragma unroll
            for (int mq = 0; mq < 2; ++mq) {
                f32x4 st[4];
                __builtin_amdgcn_s_setprio(1);
#pragma unroll
                for (int nf = 0; nf < 4; ++nf) {
                    st[nf] = (f32x4){0.f, 0.f, 0.f, 0.f};
                    st[nf] = MFMA16x16x32(kf[nf][0], qf[mq][0], st[nf]);
                    st[nf] = MFMA16x16x32(kf[nf][1], qf[mq][1], st[nf]);
                }
                __builtin_amdgcn_s_setprio(0);

                float rs = 0.f;
                unsigned pk[4][2];
#pragma unroll
                for (int nf = 0; nf < 4; ++nf) {
#pragma unroll
                    for (int r = 0; r < 4; ++r) {
                        const float p = exp2_hw(st[nf][r]);
                        st[nf][r] = p;
                        rs += p;
                    }
                    pk[nf][0] = cvtpk_bf16(st[nf][0], st[nf][1]);
                    pk[nf][1] = cvtpk_bf16(st[nf][2], st[nf][3]);
                }
                l_s[mq] += rs;

                // in-register P fragment assembly (permlane32 + permlane16 swaps)
#pragma unroll
                for (int kk = 0; kk < 2; ++kk) {
                    unsigned A = pk[2 * kk][0], C = pk[2 * kk + 1][0];
                    unsigned B = pk[2 * kk][1], D = pk[2 * kk + 1][1];
                    asm("v_permlane32_swap_b32 %0, %1" : "+v"(A), "+v"(C));
                    asm("v_permlane16_swap_b32 %0, %1" : "+v"(A), "+v"(C));
                    asm("v_permlane32_swap_b32 %0, %1" : "+v"(B), "+v"(D));
                    asm("v_permlane16_swap_b32 %0, %1" : "+v"(B), "+v"(D));
                    uint4 u;
                    u.x = A; u.y = B; u.z = C; u.w = D;   // k+{0,1},{2,3},{4,5},{6,7}
                    pf[mq][kk] = *reinterpret_cast<bf16x8*>(&u);
                }
            }

            // ---- PV: O[q][d] += P[q][k] Vt[d][k] ----
            bf16x8 vf[4][2];
#pragma unroll
            for (int df = 0; df < 4; ++df)
#pragma unroll
                for (int kk = 0; kk < 2; ++kk) {
                    const int n = df * 16 + li;
                    const int ch = kk * 4 + gg;
                    vf[df][kk] = *(const bf16x8*)(sVh + n * 64 + ((ch ^ (n & 7)) * 8));
                }
            __builtin_amdgcn_s_setprio(1);
#pragma unroll
            for (int mq = 0; mq < 2; ++mq)
#pragma unroll
                for (int df = 0; df < 4; ++df) {
                    acc[mq][df] = MFMA16x16x32(pf[mq][0], vf[df][0], acc[mq][df]);
                    acc[mq][df] = MFMA16x16x32(pf[mq][1], vf[df][1], acc[mq][df]);
                }
            __builtin_amdgcn_s_setprio(0);
        }
        __syncthreads();
    }

    // epilogue: reduce l across gg (once), O = acc / l -> [b][s][h][d] (bf16)
    const int b = bh >> 4, h = bh & 15;
#pragma unroll
    for (int mq = 0; mq < 2; ++mq) {
        float lf = l_s[mq];
        lf += __shfl_xor(lf, 16, 64);
        lf += __shfl_xor(lf, 32, 64);
#pragma unroll
        for (int r = 0; r < 4; ++r) {
            const float lbc = __shfl(lf, gg * 4 + r, 64);
            const float rl = 1.0f / lbc;
            const int q = q0 + mq * 16 + gg * 4 + r;
#pragma unroll
            for (int df = 0; df < 4; ++df) {
                const int d = df * 16 + li;
                Ob[(((size_t)b * 2048 + q) * 16 + h) * 64 + d] = f2bf(acc[mq][df][r] * rl);
            }
        }
    }
}

// ---------------- stage 6: output projection (64x128 tile, 256 blocks) --------
__global__ __launch_bounds__(256, 2) void gemm_out_kernel(
    const unsigned short* __restrict__ attn,
    const unsigned short* __restrict__ Wot,
    const float* __restrict__ bo,
    float* __restrict__ out)
{
    __shared__ unsigned short sA[2][64 * 32];
    __shared__ unsigned short sB[2][128 * 32];

    const int tid  = threadIdx.x;
    const int lane = tid & 63;
    const int w    = tid >> 6;
    const int wm   = w >> 1, wn = w & 1;   // 2 m-waves x 2 n-waves
    const int li   = lane & 15, gg = lane >> 4;
    const int m0   = blockIdx.y * 64;
    const int n0   = blockIdx.x * 128;

    const int arow = tid >> 2;             // 0..63
    const int acol = tid & 3;

    f32x4 acc[2][4];
#pragma unroll
    for (int i = 0; i < 2; ++i)
#pragma unroll
        for (int j = 0; j < 4; ++j)
            acc[i][j] = (f32x4){0.f, 0.f, 0.f, 0.f};

    int aoff[2], boff[4];
#pragma unroll
    for (int f = 0; f < 2; ++f) {
        const int ra = wm * 32 + f * 16 + li;
        aoff[f] = ra * 32 + ((gg ^ ((ra >> 1) & 3)) * 8);
    }
#pragma unroll
    for (int f = 0; f < 4; ++f) {
        const int rb = wn * 64 + f * 16 + li;
        boff[f] = rb * 32 + ((gg ^ ((rb >> 1) & 3)) * 8);
    }

    {
        const int ca = acol ^ ((arow >> 1) & 3);
        gload16(attn + (size_t)(m0 + arow) * 1024 + ca * 8, sA[0] + tid * 8);
#pragma unroll
        for (int jj = 0; jj < 2; ++jj) {
            const int rb = jj * 64 + arow;
            const int cb = acol ^ ((rb >> 1) & 3);
            gload16(Wot + (size_t)(n0 + rb) * 1024 + cb * 8, sB[0] + (jj * 256 + tid) * 8);
        }
    }
    __syncthreads();

    for (int kt = 0; kt < 32; ++kt) {
        const int cur = kt & 1;
        if (kt < 31) {
            const int k1 = (kt + 1) * 32;
            const int ca = acol ^ ((arow >> 1) & 3);
            gload16(attn + (size_t)(m0 + arow) * 1024 + k1 + ca * 8, sA[cur ^ 1] + tid * 8);
#pragma unroll
            for (int jj = 0; jj < 2; ++jj) {
                const int rb = jj * 64 + arow;
                const int cb = acol ^ ((rb >> 1) & 3);
                gload16(Wot + (size_t)(n0 + rb) * 1024 + k1 + cb * 8, sB[cur ^ 1] + (jj * 256 + tid) * 8);
            }
        }
        bf16x8 av[2], bw[4];
#pragma unroll
        for (int f = 0; f < 2; ++f) av[f] = *(const bf16x8*)(sA[cur] + aoff[f]);
#pragma unroll
        for (int f = 0; f < 4; ++f) bw[f] = *(const bf16x8*)(sB[cur] + boff[f]);
#pragma unroll
        for (int mf = 0; mf < 2; ++mf)
#pragma unroll
            for (int nf = 0; nf < 4; ++nf)
                acc[mf][nf] = MFMA16x16x32(av[mf], bw[nf], acc[mf][nf]);
        __syncthreads();
    }

#pragma unroll
    for (int nf = 0; nf < 4; ++nf) {
        const int n = n0 + wn * 64 + nf * 16 + li;
        const float bi = bo[n];
#pragma unroll
        for (int mf = 0; mf < 2; ++mf) {
#pragma unroll
            for (int r = 0; r < 4; ++r) {
                const int m = m0 + wm * 32 + mf * 16 + gg * 4 + r;
                out[(size_t)m * 512 + n] = acc[mf][nf][r] + bi;
            }
        }
    }
}

extern "C" void kernel_launch(void* const* d_in, const int* in_sizes, int n_in,
                              void* d_out, int out_size, void* d_ws, size_t ws_size,
                              hipStream_t stream) {
    const float* x  = (const float*)d_in[0];
    const float* Wq = (const float*)d_in[1];
    const float* bq = (const float*)d_in[2];
    const float* Wk = (const float*)d_in[3];
    const float* bk = (const float*)d_in[4];
    const float* Wv = (const float*)d_in[5];
    const float* bv = (const float*)d_in[6];
    const float* Wo = (const float*)d_in[7];
    const float* bo = (const float*)d_in[8];
    float* out = (float*)d_out;

    unsigned short* ws  = (unsigned short*)d_ws;
    unsigned short* xb  = ws;                  // 4096x1024
    unsigned short* Wqt = xb  + 4194304;       // 1024x1024
    unsigned short* Wkt = Wqt + 1048576;
    unsigned short* Wvt = Wkt + 1048576;
    unsigned short* Wot = Wvt + 1048576;       // 512x1024
    unsigned short* Qb  = Wot + 524288;        // [b][h][s][d]
    unsigned short* Kb  = Qb  + 4194304;
    unsigned short* Vt  = Kb  + 4194304;       // [b][h][d][s] (written by gemm_qkv)
    unsigned short* attnb = Vt + 4194304;      // [b][s][h][d]

    prep_kernel<<<dim3(7680), dim3(256), 0, stream>>>(x, xb, Wq, Wk, Wv, Wo,
                                                      Wqt, Wkt, Wvt, Wot);
    gemm_qkv_kernel<<<dim3(24, 32), dim3(256), 0, stream>>>(xb, Wqt, Wkt, Wvt,
                                                            bq, bk, bv, Qb, Kb, Vt);
    attn_kernel<<<dim3(256), dim3(512), 0, stream>>>(Qb, Kb, Vt, attnb);
    gemm_out_kernel<<<dim3(4, 64), dim3(256), 0, stream>>>(attnb, Wot, bo, out);
}

// Round 15
// 107.997 us; speedup vs baseline: 1.0032x; 1.0032x over previous
//
#include <hip/hip_runtime.h>

typedef __attribute__((ext_vector_type(8))) __bf16 bf16x8;
typedef __attribute__((ext_vector_type(4))) __bf16 bf16x4;
typedef __attribute__((ext_vector_type(4))) float f32x4;

#define MFMA16x16x32(A, B, C) __builtin_amdgcn_mfma_f32_16x16x32_bf16(A, B, C, 0, 0, 0)

__device__ __forceinline__ unsigned short f2bf(float f) {
    unsigned int u = __float_as_uint(f);
    u += 0x7fffu + ((u >> 16) & 1u);
    return (unsigned short)(u >> 16);
}

__device__ __forceinline__ unsigned cvtpk_bf16(float lo, float hi) {
    unsigned r;
    asm("v_cvt_pk_bf16_f32 %0, %1, %2" : "=v"(r) : "v"(lo), "v"(hi));
    return r;
}

// raw hardware exp2 (v_exp_f32, ~1 ulp) — avoids OCML guarded sequence (~10 instr)
__device__ __forceinline__ float exp2_hw(float x) {
    float r;
    asm("v_exp_f32 %0, %1" : "=v"(r) : "v"(x));
    return r;
}

__device__ __forceinline__ void gload16(const void* src, void* lds) {
    __builtin_amdgcn_global_load_lds(
        (const __attribute__((address_space(1))) unsigned int*)src,
        (__attribute__((address_space(3))) unsigned int*)lds,
        16, 0, 0);
}

// ---------------- stage 1+2 merged: x cvt + all W transposes, one launch -------
__global__ __launch_bounds__(256) void prep_kernel(
    const float* __restrict__ x, unsigned short* __restrict__ xb,
    const float* __restrict__ Wq, const float* __restrict__ Wk,
    const float* __restrict__ Wv, const float* __restrict__ Wo,
    unsigned short* __restrict__ Wqt, unsigned short* __restrict__ Wkt,
    unsigned short* __restrict__ Wvt, unsigned short* __restrict__ Wot)
{
    __shared__ float tile[32][33];
    const int blk = blockIdx.x;
    const int tid = threadIdx.x;

    if (blk < 4096) {
        const int i = (blk * 256 + tid) * 4;
        const float4 v = *(const float4*)(x + i);
        ushort4 o;
        o.x = f2bf(v.x); o.y = f2bf(v.y); o.z = f2bf(v.z); o.w = f2bf(v.w);
        *(ushort4*)(xb + i) = o;
        return;
    }

    const int blk2 = blk - 4096;
    const int kx = blk2 & 31;         // 0..31 k-tile
    int y = blk2 >> 5;                // 0..111
    const float* W; unsigned short* Wt; int N;
    if (y < 32)      { W = Wq; Wt = Wqt; N = 1024; }
    else if (y < 64) { W = Wk; Wt = Wkt; N = 1024; y -= 32; }
    else if (y < 96) { W = Wv; Wt = Wvt; N = 1024; y -= 64; }
    else             { W = Wo; Wt = Wot; N = 512;  y -= 96; }
    const int k0 = kx * 32;
    const int n0 = y * 32;
    const int tx = tid & 31, ty = tid >> 5;
#pragma unroll
    for (int i = 0; i < 4; ++i)
        tile[ty + 8 * i][tx] = W[(size_t)(k0 + ty + 8 * i) * N + n0 + tx];
    __syncthreads();
#pragma unroll
    for (int i = 0; i < 4; ++i)
        Wt[(size_t)(n0 + ty + 8 * i) * 1024 + k0 + tx] = f2bf(tile[tx][ty + 8 * i]);
}

// ---------------- stage 3: fused QKV GEMM ----------------
// X [4096][1024] bf16  x  Wt [1024 n][1024 k] bf16  -> Q/K [b][h][s][d] bf16 (+bias)
// V is written TRANSPOSED directly to Vt [b][h][d][s]. Q pre-scaled by log2(e)/8.
__global__ __launch_bounds__(256, 3) void gemm_qkv_kernel(
    const unsigned short* __restrict__ xb,
    const unsigned short* __restrict__ Wqt,
    const unsigned short* __restrict__ Wkt,
    const unsigned short* __restrict__ Wvt,
    const float* __restrict__ bq, const float* __restrict__ bk, const float* __restrict__ bv,
    unsigned short* __restrict__ Qb, unsigned short* __restrict__ Kb, unsigned short* __restrict__ Vt)
{
    __shared__ unsigned short sA[2][128 * 32];
    __shared__ unsigned short sB[2][128 * 32];

    const int tid  = threadIdx.x;
    const int lane = tid & 63;
    const int w    = tid >> 6;
    const int wm   = w >> 1, wn = w & 1;
    const int li   = lane & 15, gg = lane >> 4;

    // XCD swizzle: 768 blocks -> XCD c owns v in [c*96, (c+1)*96), vy-fast.
    const int L  = blockIdx.y * 24 + blockIdx.x;
    const int v  = (L & 7) * 96 + (L >> 3);
    const int vx = v >> 5;            // 0..23  (which*8 + n-panel)
    const int vy = v & 31;            // 0..31  (m-tile)
    const int m0    = vy * 128;
    const int which = vx >> 3;
    const int nloc0 = (vx & 7) * 128;

    const unsigned short* Wt = (which == 0) ? Wqt : ((which == 1) ? Wkt : Wvt);
    const float* bias        = (which == 0) ? bq  : ((which == 1) ? bk  : bv);
    const float osc          = (which == 0) ? 0.18033688011112042f : 1.0f; // log2(e)/8

    const int srow = lane >> 2;   // row within 16-row chunk
    const int schk = lane & 3;    // 16B chunk within 64B row

    f32x4 acc[4][4];
#pragma unroll
    for (int i = 0; i < 4; ++i)
#pragma unroll
        for (int j = 0; j < 4; ++j)
            acc[i][j] = (f32x4){0.f, 0.f, 0.f, 0.f};

    int aoff[4], boff[4];
#pragma unroll
    for (int f = 0; f < 4; ++f) {
        const int ra = wm * 64 + f * 16 + li;
        aoff[f] = ra * 32 + ((gg ^ ((ra >> 1) & 3)) * 8);
        const int rb = wn * 64 + f * 16 + li;
        boff[f] = rb * 32 + ((gg ^ ((rb >> 1) & 3)) * 8);
    }

#pragma unroll
    for (int j = 0; j < 2; ++j) {
        const int rl = (w * 2 + j) * 16 + srow;
        const int c  = schk ^ ((rl >> 1) & 3);
        gload16(xb + (size_t)(m0 + rl) * 1024 + c * 8,   sA[0] + (w * 2 + j) * 512);
        gload16(Wt + (size_t)(nloc0 + rl) * 1024 + c * 8, sB[0] + (w * 2 + j) * 512);
    }
    __syncthreads();

    for (int kt = 0; kt < 32; ++kt) {
        const int cur = kt & 1;
        if (kt < 31) {
            const int k1 = (kt + 1) * 32;
#pragma unroll
            for (int j = 0; j < 2; ++j) {
                const int rl = (w * 2 + j) * 16 + srow;
                const int c  = schk ^ ((rl >> 1) & 3);
                gload16(xb + (size_t)(m0 + rl) * 1024 + k1 + c * 8,   sA[cur ^ 1] + (w * 2 + j) * 512);
                gload16(Wt + (size_t)(nloc0 + rl) * 1024 + k1 + c * 8, sB[cur ^ 1] + (w * 2 + j) * 512);
            }
        }
        bf16x8 av[4], bw[4];
#pragma unroll
        for (int f = 0; f < 4; ++f) av[f] = *(const bf16x8*)(sA[cur] + aoff[f]);
#pragma unroll
        for (int f = 0; f < 4; ++f) bw[f] = *(const bf16x8*)(sB[cur] + boff[f]);
#pragma unroll
        for (int mf = 0; mf < 4; ++mf)
#pragma unroll
            for (int nf = 0; nf < 4; ++nf)
                acc[mf][nf] = MFMA16x16x32(av[mf], bw[nf], acc[mf][nf]);
        __syncthreads();
    }

    // epilogue: C frag col = lane&15, row = (lane>>4)*4 + r
    if (which == 2) {
        // V: write transposed straight to Vt[b*16+h][d][s]; r gives 4 consecutive s.
#pragma unroll
        for (int nf = 0; nf < 4; ++nf) {
            const int nl = nloc0 + wn * 64 + nf * 16 + li;
            const float bi = bias[nl];
            const int h = nl >> 6, d = nl & 63;
#pragma unroll
            for (int mf = 0; mf < 4; ++mf) {
                const int m = m0 + wm * 64 + mf * 16 + gg * 4;
                const int b = m >> 11, s0 = m & 2047;
                ushort4 o;
                o.x = f2bf(acc[mf][nf][0] + bi);
                o.y = f2bf(acc[mf][nf][1] + bi);
                o.z = f2bf(acc[mf][nf][2] + bi);
                o.w = f2bf(acc[mf][nf][3] + bi);
                *(ushort4*)(Vt + (((size_t)(b * 16 + h)) * 64 + d) * 2048 + s0) = o;
            }
        }
    } else {
        unsigned short* dst = (which == 0) ? Qb : Kb;
#pragma unroll
        for (int nf = 0; nf < 4; ++nf) {
            const int nl = nloc0 + wn * 64 + nf * 16 + li;
            const float bi = bias[nl];
            const int h = nl >> 6, d = nl & 63;
#pragma unroll
            for (int mf = 0; mf < 4; ++mf) {
#pragma unroll
                for (int r = 0; r < 4; ++r) {
                    const int m = m0 + wm * 64 + mf * 16 + gg * 4 + r;
                    const int b = m >> 11, s = m & 2047;
                    dst[(((size_t)(b * 16 + h)) * 2048 + s) * 64 + d] = f2bf((acc[mf][nf][r] + bi) * osc);
                }
            }
        }
    }
}

// ---------------- stage 5: flash attention — KVBLK=128, r9 inner x2 ----------
// 512 threads = 8 waves x 16 q; grid 512, XCD-swizzled; shift-free softmax;
// in-register P via cvt_pk + permlane swaps. Each outer iter stages a 128-key
// tile as TWO 64-key half-tiles and runs the verified inner block twice per
// barrier. Session-best measured config (47.2 us).
__global__ __launch_bounds__(512, 4) void attn_kernel(
    const unsigned short* __restrict__ Qb,
    const unsigned short* __restrict__ Kb,
    const unsigned short* __restrict__ Vt,
    unsigned short* __restrict__ Ob)
{
    __shared__ unsigned short sK[2][2][64 * 64];   // [buf][half][64 keys x 64 d]
    __shared__ unsigned short sV[2][2][64 * 64];   // [buf][half][64 d x 64 s]

    const int tid  = threadIdx.x;
    const int lane = tid & 63;
    const int w    = tid >> 6;        // 0..7
    const int li   = lane & 15, gg = lane >> 4;

    // XCD swizzle: 512 blocks, give XCD c the contiguous range v in [c*64,(c+1)*64).
    const int L  = blockIdx.y * 16 + blockIdx.x;
    const int v  = (L & 7) * 64 + (L >> 3);
    const int bh = v >> 4;
    const int q0 = (v & 15) * 128 + w * 16;

    // staging: thread stages one 16B chunk per (array, half): 4 gload16 per tile.
    const int slot = w * 64 + lane;          // 0..511
    const int srow = slot >> 3;              // 0..63
    const int schk = (slot & 7) ^ (srow & 7);

    const unsigned short* Kbase = Kb + ((size_t)bh * 2048 + srow) * 64 + schk * 8;
    const unsigned short* Vbase = Vt + ((size_t)bh * 64 + srow) * 2048 + schk * 8;

    // Q fragments (pre-scaled by log2(e)/8) in registers for whole kernel
    bf16x8 qf[2];
#pragma unroll
    for (int kk = 0; kk < 2; ++kk) {
        const int q = q0 + li;
        const int d = kk * 32 + gg * 8;
        qf[kk] = *(const bf16x8*)(Qb + ((size_t)bh * 2048 + q) * 64 + d);
    }

    f32x4 acc[4];
#pragma unroll
    for (int df = 0; df < 4; ++df) acc[df] = (f32x4){0.f, 0.f, 0.f, 0.f};
    float l_s = 0.f;   // per-lane partial sum (lane's 16-k subset of q=li's row)

    // prologue: stage tile 0 (both 64-key halves)
    gload16(Kbase,                     sK[0][0] + slot * 8);
    gload16(Kbase + 64 * 64,           sK[0][1] + slot * 8);
    gload16(Vbase,                     sV[0][0] + slot * 8);
    gload16(Vbase + 64,                sV[0][1] + slot * 8);
    __syncthreads();

    for (int tt = 0; tt < 16; ++tt) {
        const int cur = tt & 1;
        if (tt < 15) {
            const size_t ko = (size_t)(tt + 1) * 8192;   // 128 keys * 64 d
            const size_t vo = (size_t)(tt + 1) * 128;    // 128 s
            gload16(Kbase + ko,            sK[cur ^ 1][0] + slot * 8);
            gload16(Kbase + ko + 4096,     sK[cur ^ 1][1] + slot * 8);
            gload16(Vbase + vo,            sV[cur ^ 1][0] + slot * 8);
            gload16(Vbase + vo + 64,       sV[cur ^ 1][1] + slot * 8);
        }

#pragma unroll
        for (int sub = 0; sub < 2; ++sub) {
            const unsigned short* sKh = sK[cur][sub];
            const unsigned short* sVh = sV[cur][sub];

            // ---- S^T = mfma(K, Q): st[nf], q = q0+li, k = nf*16 + gg*4 + r ----
            bf16x8 kf[4][2];
#pragma unroll
            for (int nf = 0; nf < 4; ++nf)
#pragma unroll
                for (int kk = 0; kk < 2; ++kk) {
                    const int n = nf * 16 + li;
                    const int ch = kk * 4 + gg;
                    kf[nf][kk] = *(const bf16x8*)(sKh + n * 64 + ((ch ^ (n & 7)) * 8));
                }
            f32x4 st[4];
            __builtin_amdgcn_s_setprio(1);
#pragma unroll
            for (int nf = 0; nf < 4; ++nf) {
                st[nf] = (f32x4){0.f, 0.f, 0.f, 0.f};
                st[nf] = MFMA16x16x32(kf[nf][0], qf[0], st[nf]);
                st[nf] = MFMA16x16x32(kf[nf][1], qf[1], st[nf]);
            }
            __builtin_amdgcn_s_setprio(0);

            // ---- shift-free softmax numerator: P = exp2(s'), partial l in-lane ----
            float rs = 0.f;
            unsigned pk[4][2];
#pragma unroll
            for (int nf = 0; nf < 4; ++nf) {
#pragma unroll
                for (int r = 0; r < 4; ++r) {
                    const float p = exp2_hw(st[nf][r]);
                    st[nf][r] = p;
                    rs += p;
                }
                pk[nf][0] = cvtpk_bf16(st[nf][0], st[nf][1]);
                pk[nf][1] = cvtpk_bf16(st[nf][2], st[nf][3]);
            }
            l_s += rs;

            // ---- in-register P fragment assembly (permlane32 + permlane16 swaps) ----
            bf16x8 pf[2];
#pragma unroll
            for (int kk = 0; kk < 2; ++kk) {
                unsigned A = pk[2 * kk][0], C = pk[2 * kk + 1][0];
                unsigned B = pk[2 * kk][1], D = pk[2 * kk + 1][1];
                asm("v_permlane32_swap_b32 %0, %1" : "+v"(A), "+v"(C));
                asm("v_permlane16_swap_b32 %0, %1" : "+v"(A), "+v"(C));
                asm("v_permlane32_swap_b32 %0, %1" : "+v"(B), "+v"(D));
                asm("v_permlane16_swap_b32 %0, %1" : "+v"(B), "+v"(D));
                uint4 u;
                u.x = A; u.y = B; u.z = C; u.w = D;   // words: k+{0,1},{2,3},{4,5},{6,7}
                pf[kk] = *reinterpret_cast<bf16x8*>(&u);
            }

            // ---- PV: O[q][d] += P[q][k] Vt[d][k] ----
            bf16x8 vf[4][2];
#pragma unroll
            for (int df = 0; df < 4; ++df)
#pragma unroll
                for (int kk = 0; kk < 2; ++kk) {
                    const int n = df * 16 + li;
                    const int ch = kk * 4 + gg;
                    vf[df][kk] = *(const bf16x8*)(sVh + n * 64 + ((ch ^ (n & 7)) * 8));
                }
            __builtin_amdgcn_s_setprio(1);
#pragma unroll
            for (int df = 0; df < 4; ++df) {
                acc[df] = MFMA16x16x32(pf[0], vf[df][0], acc[df]);
                acc[df] = MFMA16x16x32(pf[1], vf[df][1], acc[df]);
            }
            __builtin_amdgcn_s_setprio(0);
        }
        __syncthreads();
    }

    // epilogue: reduce l across gg (once), O = acc / l -> [b][s][h][d] (bf16)
    float lf = l_s;
    lf += __shfl_xor(lf, 16, 64);
    lf += __shfl_xor(lf, 32, 64);

    const int b = bh >> 4, h = bh & 15;
#pragma unroll
    for (int r = 0; r < 4; ++r) {
        const float lbc = __shfl(lf, gg * 4 + r, 64);
        const float rl = 1.0f / lbc;
        const int q = q0 + gg * 4 + r;
#pragma unroll
        for (int df = 0; df < 4; ++df) {
            const int d = df * 16 + li;
            Ob[(((size_t)b * 2048 + q) * 16 + h) * 64 + d] = f2bf(acc[df][r] * rl);
        }
    }
}

// ---------------- stage 6: output projection (64x128 tile, 256 blocks) --------
__global__ __launch_bounds__(256, 2) void gemm_out_kernel(
    const unsigned short* __restrict__ attn,
    const unsigned short* __restrict__ Wot,
    const float* __restrict__ bo,
    float* __restrict__ out)
{
    __shared__ unsigned short sA[2][64 * 32];
    __shared__ unsigned short sB[2][128 * 32];

    const int tid  = threadIdx.x;
    const int lane = tid & 63;
    const int w    = tid >> 6;
    const int wm   = w >> 1, wn = w & 1;   // 2 m-waves x 2 n-waves
    const int li   = lane & 15, gg = lane >> 4;
    const int m0   = blockIdx.y * 64;
    const int n0   = blockIdx.x * 128;

    const int arow = tid >> 2;             // 0..63
    const int acol = tid & 3;

    f32x4 acc[2][4];
#pragma unroll
    for (int i = 0; i < 2; ++i)
#pragma unroll
        for (int j = 0; j < 4; ++j)
            acc[i][j] = (f32x4){0.f, 0.f, 0.f, 0.f};

    int aoff[2], boff[4];
#pragma unroll
    for (int f = 0; f < 2; ++f) {
        const int ra = wm * 32 + f * 16 + li;
        aoff[f] = ra * 32 + ((gg ^ ((ra >> 1) & 3)) * 8);
    }
#pragma unroll
    for (int f = 0; f < 4; ++f) {
        const int rb = wn * 64 + f * 16 + li;
        boff[f] = rb * 32 + ((gg ^ ((rb >> 1) & 3)) * 8);
    }

    {
        const int ca = acol ^ ((arow >> 1) & 3);
        gload16(attn + (size_t)(m0 + arow) * 1024 + ca * 8, sA[0] + tid * 8);
#pragma unroll
        for (int jj = 0; jj < 2; ++jj) {
            const int rb = jj * 64 + arow;
            const int cb = acol ^ ((rb >> 1) & 3);
            gload16(Wot + (size_t)(n0 + rb) * 1024 + cb * 8, sB[0] + (jj * 256 + tid) * 8);
        }
    }
    __syncthreads();

    for (int kt = 0; kt < 32; ++kt) {
        const int cur = kt & 1;
        if (kt < 31) {
            const int k1 = (kt + 1) * 32;
            const int ca = acol ^ ((arow >> 1) & 3);
            gload16(attn + (size_t)(m0 + arow) * 1024 + k1 + ca * 8, sA[cur ^ 1] + tid * 8);
#pragma unroll
            for (int jj = 0; jj < 2; ++jj) {
                const int rb = jj * 64 + arow;
                const int cb = acol ^ ((rb >> 1) & 3);
                gload16(Wot + (size_t)(n0 + rb) * 1024 + k1 + cb * 8, sB[cur ^ 1] + (jj * 256 + tid) * 8);
            }
        }
        bf16x8 av[2], bw[4];
#pragma unroll
        for (int f = 0; f < 2; ++f) av[f] = *(const bf16x8*)(sA[cur] + aoff[f]);
#pragma unroll
        for (int f = 0; f < 4; ++f) bw[f] = *(const bf16x8*)(sB[cur] + boff[f]);
#pragma unroll
        for (int mf = 0; mf < 2; ++mf)
#pragma unroll
            for (int nf = 0; nf < 4; ++nf)
                acc[mf][nf] = MFMA16x16x32(av[mf], bw[nf], acc[mf][nf]);
        __syncthreads();
    }

#pragma unroll
    for (int nf = 0; nf < 4; ++nf) {
        const int n = n0 + wn * 64 + nf * 16 + li;
        const float bi = bo[n];
#pragma unroll
        for (int mf = 0; mf < 2; ++mf) {
#pragma unroll
            for (int r = 0; r < 4; ++r) {
                const int m = m0 + wm * 32 + mf * 16 + gg * 4 + r;
                out[(size_t)m * 512 + n] = acc[mf][nf][r] + bi;
            }
        }
    }
}

extern "C" void kernel_launch(void* const* d_in, const int* in_sizes, int n_in,
                              void* d_out, int out_size, void* d_ws, size_t ws_size,
                              hipStream_t stream) {
    const float* x  = (const float*)d_in[0];
    const float* Wq = (const float*)d_in[1];
    const float* bq = (const float*)d_in[2];
    const float* Wk = (const float*)d_in[3];
    const float* bk = (const float*)d_in[4];
    const float* Wv = (const float*)d_in[5];
    const float* bv = (const float*)d_in[6];
    const float* Wo = (const float*)d_in[7];
    const float* bo = (const float*)d_in[8];
    float* out = (float*)d_out;

    unsigned short* ws  = (unsigned short*)d_ws;
    unsigned short* xb  = ws;                  // 4096x1024
    unsigned short* Wqt = xb  + 4194304;       // 1024x1024
    unsigned short* Wkt = Wqt + 1048576;
    unsigned short* Wvt = Wkt + 1048576;
    unsigned short* Wot = Wvt + 1048576;       // 512x1024
    unsigned short* Qb  = Wot + 524288;        // [b][h][s][d]
    unsigned short* Kb  = Qb  + 4194304;
    unsigned short* Vt  = Kb  + 4194304;       // [b][h][d][s] (written by gemm_qkv)
    unsigned short* attnb = Vt + 4194304;      // [b][s][h][d]

    prep_kernel<<<dim3(7680), dim3(256), 0, stream>>>(x, xb, Wq, Wk, Wv, Wo,
                                                      Wqt, Wkt, Wvt, Wot);
    gemm_qkv_kernel<<<dim3(24, 32), dim3(256), 0, stream>>>(xb, Wqt, Wkt, Wvt,
                                                            bq, bk, bv, Qb, Kb, Vt);
    attn_kernel<<<dim3(16, 32), dim3(512), 0, stream>>>(Qb, Kb, Vt, attnb);
    gemm_out_kernel<<<dim3(4, 64), dim3(256), 0, stream>>>(attnb, Wot, bo, out);
}